// Round 4
// baseline (366.759 us; speedup 1.0000x reference)
//
#include <hip/hip_runtime.h>

// Problem: B=16384, F=1024, H=64, D=256, TE=CE=4.
// I/O dtype: float32. Internal compute: fp16 MFMA, fp32 accum.
// out = (outA, outS, outB), each [B, 256] fp32, concatenated in d_out.

#define BB 16384
#define FF 1024

typedef _Float16 f16;
typedef __fp16 h16x2 __attribute__((ext_vector_type(2)));   // cvt_pkrtz return type
typedef _Float16 f16x8 __attribute__((ext_vector_type(8)));
typedef float f32x4 __attribute__((ext_vector_type(4)));

// async global->LDS, 16B per lane. LDS dest must be wave-uniform base + lane*16.
__device__ __forceinline__ void load_lds16(const void* g, void* l) {
    __builtin_amdgcn_global_load_lds(
        (const __attribute__((address_space(1))) unsigned int*)g,
        (__attribute__((address_space(3))) unsigned int*)l, 16, 0, 0);
}

__device__ __forceinline__ f16x8 pack8(float4 lo, float4 hi) {
    union { f16x8 v; h16x2 p[4]; } u;
    u.p[0] = __builtin_amdgcn_cvt_pkrtz(lo.x, lo.y);
    u.p[1] = __builtin_amdgcn_cvt_pkrtz(lo.z, lo.w);
    u.p[2] = __builtin_amdgcn_cvt_pkrtz(hi.x, hi.y);
    u.p[3] = __builtin_amdgcn_cvt_pkrtz(hi.z, hi.w);
    return u.v;
}

// ---------------------------------------------------------------------------
// Pack: Wp[g][c][k]  = (f16)W1g[e=c>>6][k][h=c&63]    (3 x 256 x 1024)
//       W2T[g][e][d][h] = (f16)W2g[e][h][d]           (3 x 4 x 256 x 64)
//       Gp2[g][c][k] = (f16)Wgg[k][c] (zero-pad c>=ng) (3 x 16 x 1024)
// ---------------------------------------------------------------------------
__global__ __launch_bounds__(256) void pack_kernel(
    const float* __restrict__ W1A, const float* __restrict__ W1S, const float* __restrict__ W1B,
    const float* __restrict__ W2A, const float* __restrict__ W2S, const float* __restrict__ W2B,
    const float* __restrict__ WgA, const float* __restrict__ WgS, const float* __restrict__ WgB,
    f16* __restrict__ Wp, f16* __restrict__ W2T, f16* __restrict__ Gp2)
{
    int idx = blockIdx.x * 256 + threadIdx.x;
    if (idx < 786432) {
        int g = idx / 262144, rem = idx % 262144;
        int c = rem >> 10, k = rem & 1023;
        const float* W1 = (g == 0) ? W1A : ((g == 1) ? W1S : W1B);
        Wp[idx] = (f16)W1[((c >> 6) << 16) + k * 64 + (c & 63)];
    } else if (idx < 983040) {
        int j = idx - 786432;
        int g = j / 65536, rem = j % 65536;
        int e = rem >> 14, rr = rem & 16383;
        int d = rr >> 6, hh = rr & 63;
        const float* W2 = (g == 0) ? W2A : ((g == 1) ? W2S : W2B);
        W2T[j] = (f16)W2[e * 16384 + hh * 256 + d];
    } else {
        int j = idx - 983040;                 // < 3*16*1024
        int g = j / 16384, rem = j % 16384;
        int c = rem >> 10, k = rem & 1023;
        int ng = (g == 1) ? 12 : 8;
        const float* Wg = (g == 0) ? WgA : ((g == 1) ? WgS : WgB);
        Gp2[j] = (c < ng) ? (f16)Wg[k * ng + c] : (f16)0.0f;
    }
}

// ---------------------------------------------------------------------------
// Layer-1: h_g = relu(x_g @ W1cat_g + b1_g) -> fp16 h [3][B][256], plus gate
// softmax for each block's own 128 rows. Block = 128 rows x 256 cols (full N),
// 512 threads (8 waves, 2x4). Double-buffered LDS: sync; prefetch(next);
// compute(cur). Gate B-frag read global->reg from Gp2. grid (128, 3).
// ---------------------------------------------------------------------------
__global__ __launch_bounds__(512, 4) void l1_kernel(
    const float* __restrict__ xA, const float* __restrict__ xS, const float* __restrict__ xB,
    const float* __restrict__ b1A, const float* __restrict__ b1S, const float* __restrict__ b1B,
    const float* __restrict__ bgA, const float* __restrict__ bgS, const float* __restrict__ bgB,
    const f16* __restrict__ Wp,      // [3][256][1024]
    const f16* __restrict__ Gp2,     // [3][16][1024]
    f16* __restrict__ hbuf,          // [3][B][256]
    float* __restrict__ gates)       // gA[B][8] | gS[B][12] | gB[B][8]
{
    const int g = blockIdx.y;
    const float* x  = (g == 0) ? xA  : ((g == 1) ? xS  : xB);
    const float* b1 = (g == 0) ? b1A : ((g == 1) ? b1S : b1B);
    const float* bg = (g == 0) ? bgA : ((g == 1) ? bgS : bgB);
    const int ng = (g == 1) ? 12 : 8;
    float* gout = gates + ((g == 0) ? (size_t)0
                         : (g == 1) ? (size_t)BB * 8
                                    : (size_t)BB * 8 + (size_t)BB * 12);

    const int row0 = blockIdx.x * 128;

    __shared__ __align__(16) float Asf[2][128 * 32];   // fp32 x tile, swizzled
    __shared__ __align__(16) f16   Bsh[2][256 * 32];   // f16 weights [n][k], swizzled

    const int tid  = threadIdx.x;
    const int lane = tid & 63;
    const int wave = tid >> 6;
    const int wm = (wave >> 2) * 64;
    const int wn = (wave & 3) * 64;
    const int lrow = lane & 15;
    const int quad = lane >> 4;
    const bool my_gate = ((wave & 3) == 0);

    const f16* Wgrp = Wp + (size_t)g * 256 * 1024;
    const f16* Ggrp = Gp2 + ((size_t)g * 16 + lrow) * 1024 + quad * 8;
    const float* xrow = x + (size_t)row0 * FF;

    f32x4 acc[4][4] = {};
    f32x4 gacc[4] = {};

    // ---- prefetch k0 = 0 into buf 0 ----
#pragma unroll
    for (int r = 0; r < 2; ++r) {
        int s = r * 512 + tid;
        int m = s >> 3, slot = s & 7;
        int seg = slot ^ (m & 7);
        load_lds16(xrow + (size_t)m * FF + seg * 4, &Asf[0][s * 4]);
    }
#pragma unroll
    for (int r = 0; r < 2; ++r) {
        int s = r * 512 + tid;
        int n = s >> 2, slot = s & 3;
        int seg = slot ^ ((n >> 1) & 3);
        load_lds16(Wgrp + (size_t)n * FF + seg * 8, &Bsh[0][s * 8]);
    }

    int cur = 0;
    for (int k0 = 0; k0 < FF; k0 += 32) {
        __syncthreads();            // buf[cur] arrived; buf[cur^1] free
        int nxt = cur ^ 1;
        if (k0 + 32 < FF) {
#pragma unroll
            for (int r = 0; r < 2; ++r) {
                int s = r * 512 + tid;
                int m = s >> 3, slot = s & 7;
                int seg = slot ^ (m & 7);
                load_lds16(xrow + (size_t)m * FF + (k0 + 32) + seg * 4, &Asf[nxt][s * 4]);
            }
#pragma unroll
            for (int r = 0; r < 2; ++r) {
                int s = r * 512 + tid;
                int n = s >> 2, slot = s & 3;
                int seg = slot ^ ((n >> 1) & 3);
                load_lds16(Wgrp + (size_t)n * FF + (k0 + 32) + seg * 8, &Bsh[nxt][s * 8]);
            }
        }

        f16x8 gb;
        if (my_gate) gb = *(const f16x8*)(Ggrp + k0);   // global->reg, L2-hot

        f16x8 af[4];
#pragma unroll
        for (int i = 0; i < 4; ++i) {
            int m = wm + i * 16 + lrow;
            const float* rp = &Asf[cur][m * 32];
            int s0 = (2 * quad) ^ (m & 7);
            float4 lo = *(const float4*)(rp + s0 * 4);
            float4 hi = *(const float4*)(rp + (s0 ^ 1) * 4);
            af[i] = pack8(lo, hi);
        }
#pragma unroll
        for (int j = 0; j < 4; ++j) {
            int n = wn + j * 16 + lrow;
            int slot = quad ^ ((n >> 1) & 3);
            f16x8 bf = *(const f16x8*)(&Bsh[cur][n * 32 + slot * 8]);
#pragma unroll
            for (int i = 0; i < 4; ++i)
                acc[i][j] = __builtin_amdgcn_mfma_f32_16x16x32_f16(af[i], bf, acc[i][j], 0, 0, 0);
        }
        if (my_gate) {
#pragma unroll
            for (int i = 0; i < 4; ++i)
                gacc[i] = __builtin_amdgcn_mfma_f32_16x16x32_f16(af[i], gb, gacc[i], 0, 0, 0);
        }
        cur = nxt;
    }

    // epilogue: h = relu(acc + b1), fp16. C/D: col=lane&15, row=quad*4+reg.
#pragma unroll
    for (int j = 0; j < 4; ++j) {
        int c = wn + j * 16 + lrow;
        float bias = b1[c];
#pragma unroll
        for (int i = 0; i < 4; ++i) {
#pragma unroll
            for (int r = 0; r < 4; ++r) {
                int row = row0 + wm + i * 16 + quad * 4 + r;
                float v = fmaxf(acc[i][j][r] + bias, 0.0f);
                hbuf[((size_t)g * BB + row) * 256 + c] = (f16)v;
            }
        }
    }

    // gate softmax: 16-lane groups share one row's logits (c = lrow)
    if (my_gate) {
        int c = lrow;
        bool valid = (c < ng);
        float bias = valid ? bg[c] : 0.0f;
#pragma unroll
        for (int i = 0; i < 4; ++i) {
#pragma unroll
            for (int r = 0; r < 4; ++r) {
                int row = row0 + wm + i * 16 + quad * 4 + r;
                float logit = valid ? (gacc[i][r] + bias) : -1e30f;
                float mx = logit;
#pragma unroll
                for (int m = 1; m < 16; m <<= 1)
                    mx = fmaxf(mx, __shfl_xor(mx, m, 16));
                float ev = valid ? __expf(logit - mx) : 0.0f;
                float sum = ev;
#pragma unroll
                for (int m = 1; m < 16; m <<= 1)
                    sum += __shfl_xor(sum, m, 16);
                if (valid) gout[(size_t)row * ng + c] = ev / sum;
            }
        }
    }
}

// ---------------------------------------------------------------------------
// Layer-2 + gated combine. LDS-free (gates only). grid (256, 3), 512 threads.
// Block: 64 rows x 256 cols of output o. 8 waves: (wave>>2) picks 32-row half,
// (wave&3) picks 64-col quarter. Per expert: h and W2T fragments loaded
// global->reg (L2/LLC-hot), 2 MFMAs per (i,j), relu+gate fold into oacc.
// ---------------------------------------------------------------------------
__global__ __launch_bounds__(512) void l2_kernel(
    const f16* __restrict__ hbuf,    // [3][B][256]
    const f16* __restrict__ W2T,     // [3][4][256][64]
    const float* __restrict__ b2A, const float* __restrict__ b2S, const float* __restrict__ b2B,
    const float* __restrict__ gates,
    float* __restrict__ out)         // [3][B][256] (A,S,B)
{
    const int o = blockIdx.y;
    const int row0 = blockIdx.x * 64;
    const int tid = threadIdx.x;
    const int lane = tid & 63;
    const int wave = tid >> 6;
    const int wm = (wave >> 2) * 32;
    const int wn = (wave & 3) * 64;
    const int lrow = lane & 15;
    const int quad = lane >> 4;

    const int ng = (o == 1) ? 12 : 8;
    const float* gp = gates + ((o == 0) ? (size_t)0
                             : (o == 1) ? (size_t)BB * 8
                                        : (size_t)BB * 8 + (size_t)BB * 12);

    __shared__ float gsh[64 * 12];
    for (int idx = tid; idx < 64 * ng; idx += 512)
        gsh[idx] = gp[(size_t)(row0 + idx / ng) * ng + (idx % ng)];
    __syncthreads();

    f32x4 oacc[2][4] = {};

    for (int k = 0; k < ng; ++k) {
        int e = k & 3, gi;
        if (o == 0)      gi = (k < 4) ? 0 : 1;   // concat([EA, ES])
        else if (o == 1) gi = k >> 2;            // concat([EA, ES, EB])
        else             gi = (k < 4) ? 2 : 1;   // concat([EB, ES])

        const f16* hs = hbuf + ((size_t)gi * BB + row0 + wm) * 256 + e * 64;
        const f16* w2 = W2T + (size_t)(gi * 4 + e) * 256 * 64;
        const float* b2 = (gi == 0) ? b2A : ((gi == 1) ? b2S : b2B);

        // A-frags: rows wm+i*16+lrow, k = kk*32 + quad*8
        f16x8 af[2][2];
#pragma unroll
        for (int i = 0; i < 2; ++i)
#pragma unroll
            for (int kk = 0; kk < 2; ++kk)
                af[i][kk] = *(const f16x8*)(hs + (size_t)(i * 16 + lrow) * 256 + kk * 32 + quad * 8);

#pragma unroll
        for (int j = 0; j < 4; ++j) {
            int d = wn + j * 16 + lrow;
            f16x8 bf0 = *(const f16x8*)(w2 + (size_t)d * 64 + quad * 8);
            f16x8 bf1 = *(const f16x8*)(w2 + (size_t)d * 64 + 32 + quad * 8);
            float bias = b2[e * 256 + d];
#pragma unroll
            for (int i = 0; i < 2; ++i) {
                f32x4 t = {};
                t = __builtin_amdgcn_mfma_f32_16x16x32_f16(af[i][0], bf0, t, 0, 0, 0);
                t = __builtin_amdgcn_mfma_f32_16x16x32_f16(af[i][1], bf1, t, 0, 0, 0);
#pragma unroll
                for (int r = 0; r < 4; ++r) {
                    int rl = wm + i * 16 + quad * 4 + r;
                    float v = fmaxf(t[r] + bias, 0.0f);
                    oacc[i][j][r] += gsh[rl * ng + k] * v;
                }
            }
        }
    }

#pragma unroll
    for (int j = 0; j < 4; ++j) {
        int d = wn + j * 16 + lrow;
#pragma unroll
        for (int i = 0; i < 2; ++i) {
#pragma unroll
            for (int r = 0; r < 4; ++r) {
                int rl = wm + i * 16 + quad * 4 + r;
                out[((size_t)o * BB + row0 + rl) * 256 + d] = oacc[i][j][r];
            }
        }
    }
}

// ---------------------------------------------------------------------------
extern "C" void kernel_launch(void* const* d_in, const int* in_sizes, int n_in,
                              void* d_out, int out_size, void* d_ws, size_t ws_size,
                              hipStream_t stream)
{
    (void)in_sizes; (void)n_in; (void)out_size; (void)ws_size;

    const float* xA  = (const float*)d_in[0];
    const float* xS  = (const float*)d_in[1];
    const float* xB  = (const float*)d_in[2];
    const float* W1A = (const float*)d_in[3];
    const float* b1A = (const float*)d_in[4];
    const float* W2A = (const float*)d_in[5];
    const float* b2A = (const float*)d_in[6];
    const float* W1S = (const float*)d_in[7];
    const float* b1S = (const float*)d_in[8];
    const float* W2S = (const float*)d_in[9];
    const float* b2S = (const float*)d_in[10];
    const float* W1B = (const float*)d_in[11];
    const float* b1B = (const float*)d_in[12];
    const float* W2B = (const float*)d_in[13];
    const float* b2B = (const float*)d_in[14];
    const float* WgA = (const float*)d_in[15];
    const float* bgA = (const float*)d_in[16];
    const float* WgB = (const float*)d_in[17];
    const float* bgB = (const float*)d_in[18];
    const float* WgS = (const float*)d_in[19];
    const float* bgS = (const float*)d_in[20];

    char* ws = (char*)d_ws;
    f16*   Wp   = (f16*)(ws);                       // 1,572,864 B
    f16*   W2T  = (f16*)(ws + 0x180000);            //   393,216 B
    f16*   Gp2  = (f16*)(ws + 0x1E0000);            //    98,304 B
    f16*   hbuf = (f16*)(ws + 0x200000);            // 25,165,824 B
    float* gate = (float*)(ws + 0x200000 + 0x1800000); // 1,835,008 B

    pack_kernel<<<4032, 256, 0, stream>>>(W1A, W1S, W1B, W2A, W2S, W2B,
                                          WgA, WgS, WgB, Wp, W2T, Gp2);
    l1_kernel<<<dim3(128, 3), 512, 0, stream>>>(
        xA, xS, xB, b1A, b1S, b1B, bgA, bgS, bgB,
        Wp, Gp2, hbuf, gate);
    l2_kernel<<<dim3(256, 3), 512, 0, stream>>>(
        hbuf, W2T, b2A, b2S, b2B, gate, (float*)d_out);
}

// Round 5
// 342.419 us; speedup vs baseline: 1.0711x; 1.0711x over previous
//
#include <hip/hip_runtime.h>

// Problem: B=16384, F=1024, H=64, D=256, TE=CE=4.
// I/O dtype: float32. Internal compute: fp16 MFMA, fp32 accum.
// out = (outA, outS, outB), each [B, 256] fp32, concatenated in d_out.

#define BB 16384
#define FF 1024

typedef _Float16 f16;
typedef __fp16 h16x2 __attribute__((ext_vector_type(2)));   // cvt_pkrtz return type
typedef _Float16 f16x8 __attribute__((ext_vector_type(8)));
typedef float f32x4 __attribute__((ext_vector_type(4)));

// async global->LDS, 16B per lane. LDS dest must be wave-uniform base + lane*16.
__device__ __forceinline__ void load_lds16(const void* g, void* l) {
    __builtin_amdgcn_global_load_lds(
        (const __attribute__((address_space(1))) unsigned int*)g,
        (__attribute__((address_space(3))) unsigned int*)l, 16, 0, 0);
}

__device__ __forceinline__ f16x8 pack8(float4 lo, float4 hi) {
    union { f16x8 v; h16x2 p[4]; } u;
    u.p[0] = __builtin_amdgcn_cvt_pkrtz(lo.x, lo.y);
    u.p[1] = __builtin_amdgcn_cvt_pkrtz(lo.z, lo.w);
    u.p[2] = __builtin_amdgcn_cvt_pkrtz(hi.x, hi.y);
    u.p[3] = __builtin_amdgcn_cvt_pkrtz(hi.z, hi.w);
    return u.v;
}

// expert k of output o lives in group gi (0=A,1=S,2=B)
__device__ __forceinline__ int expert_gi(int o, int k) {
    if (o == 0) return (k < 4) ? 0 : 1;     // concat([EA, ES])
    if (o == 1) return k >> 2;              // concat([EA, ES, EB])
    return (k < 4) ? 2 : 1;                 // concat([EB, ES])
}

// ---------------------------------------------------------------------------
// Pack to MFMA B-fragment order (lane n_low=lane&15, k=quad*8+j):
//  W1F[g][nt:16][kt:32][lane:64][j:8],  col c=nt*16+(lane&15) (=e*64+h),
//      k=kt*32+(lane>>4)*8+j,  src W1g[e][k][h]
//  W2F[g][e][nt:16][kt:2][lane:64][j:8], d=nt*16+(lane&15), hh=kt*32+(lane>>4)*8+j,
//      src W2g[e][hh][d]
//  Gp2[g][c:16][k:1024] zero-padded, src Wgg[k][c]
// ---------------------------------------------------------------------------
__global__ __launch_bounds__(256) void pack_kernel(
    const float* __restrict__ W1A, const float* __restrict__ W1S, const float* __restrict__ W1B,
    const float* __restrict__ W2A, const float* __restrict__ W2S, const float* __restrict__ W2B,
    const float* __restrict__ WgA, const float* __restrict__ WgS, const float* __restrict__ WgB,
    f16* __restrict__ W1F, f16* __restrict__ W2F, f16* __restrict__ Gp2)
{
    int idx = blockIdx.x * 256 + threadIdx.x;
    if (idx < 786432) {
        int g = idx / 262144, r = idx % 262144;
        int nt = r >> 14, r2 = r & 16383;
        int kt = r2 >> 9, s = r2 & 511;
        int lane = s >> 3, j = s & 7;
        int c = nt * 16 + (lane & 15);
        int k = kt * 32 + (lane >> 4) * 8 + j;
        const float* W1 = (g == 0) ? W1A : ((g == 1) ? W1S : W1B);
        W1F[idx] = (f16)W1[((c >> 6) << 16) + k * 64 + (c & 63)];
    } else if (idx < 983040) {
        int t = idx - 786432;                // 3*4*16*2*512 = 196608
        int g = t / 65536, r = t % 65536;
        int e = r >> 14, r2 = r & 16383;
        int nt = r2 >> 10, r3 = r2 & 1023;
        int kt = r3 >> 9, s = r3 & 511;
        int lane = s >> 3, j = s & 7;
        int d = nt * 16 + (lane & 15);
        int hh = kt * 32 + (lane >> 4) * 8 + j;
        const float* W2 = (g == 0) ? W2A : ((g == 1) ? W2S : W2B);
        W2F[t] = (f16)W2[e * 16384 + hh * 256 + d];
    } else {
        int t = idx - 983040;                // 3*16*1024 = 49152
        int g = t / 16384, rem = t % 16384;
        int c = rem >> 10, k = rem & 1023;
        int ng = (g == 1) ? 12 : 8;
        const float* Wg = (g == 0) ? WgA : ((g == 1) ? WgS : WgB);
        Gp2[t] = (c < ng) ? (f16)Wg[k * ng + c] : (f16)0.0f;
    }
}

// ---------------------------------------------------------------------------
// Layer-1: h_g = relu(x_g @ W1cat_g + b1_g) -> fp16 h [3][B][256] + fused gate
// softmax. Block = 128 rows x 256 cols, 512 threads (8 waves 2x4).
// x: reg-staged pipeline (global fp32 -> cvt -> ds_write f16, dbuf, 1 barrier/iter).
// W1: B-frag-packed, coalesced global->reg, no LDS. grid (128, 3).
// ---------------------------------------------------------------------------
__global__ __launch_bounds__(512, 4) void l1_kernel(
    const float* __restrict__ xA, const float* __restrict__ xS, const float* __restrict__ xB,
    const float* __restrict__ b1A, const float* __restrict__ b1S, const float* __restrict__ b1B,
    const float* __restrict__ bgA, const float* __restrict__ bgS, const float* __restrict__ bgB,
    const f16* __restrict__ W1F,     // [3][16][32][64][8]
    const f16* __restrict__ Gp2,     // [3][16][1024]
    f16* __restrict__ hbuf,          // [3][B][256]
    float* __restrict__ gates)       // gA[B][8] | gS[B][12] | gB[B][8]
{
    const int g = blockIdx.y;
    const float* x  = (g == 0) ? xA  : ((g == 1) ? xS  : xB);
    const float* b1 = (g == 0) ? b1A : ((g == 1) ? b1S : b1B);
    const float* bg = (g == 0) ? bgA : ((g == 1) ? bgS : bgB);
    const int ng = (g == 1) ? 12 : 8;
    float* gout = gates + ((g == 0) ? (size_t)0
                         : (g == 1) ? (size_t)BB * 8
                                    : (size_t)BB * 8 + (size_t)BB * 12);

    const int row0 = blockIdx.x * 128;

    __shared__ __align__(16) f16 Ash[2][128 * 32];   // f16 x tile, 8 KB per buf

    const int tid  = threadIdx.x;
    const int lane = tid & 63;
    const int wave = tid >> 6;
    const int wm = (wave >> 2) * 64;
    const int wn = (wave & 3) * 64;
    const int lrow = lane & 15;
    const int quad = lane >> 4;
    const bool my_gate = ((wave & 3) == 0);

    const f16* Wbase = W1F + (size_t)g * 262144;
    const f16* Ggrp  = Gp2 + ((size_t)g * 16 + lrow) * 1024 + quad * 8;

    // x staging assignment: thread -> (row am, 8-float chunk ac)
    const int am = tid >> 2;
    const int ac = tid & 3;
    const float* xld = x + (size_t)(row0 + am) * FF + ac * 8;
    const int aoff = am * 32 + ac * 8;

    f32x4 acc[4][4] = {};
    f32x4 gacc[4] = {};

    // prime: kt=0 into buf 0
    {
        float4 lo = *(const float4*)(xld);
        float4 hi = *(const float4*)(xld + 4);
        *(f16x8*)(&Ash[0][aoff]) = pack8(lo, hi);
    }
    __syncthreads();

    for (int kt = 0; kt < 32; ++kt) {
        const int cur = kt & 1, nxt = cur ^ 1;
        float4 lo, hi;
        if (kt < 31) {                       // issue next x loads early
            lo = *(const float4*)(xld + (kt + 1) * 32);
            hi = *(const float4*)(xld + (kt + 1) * 32 + 4);
        }
        f16x8 gb;
        if (my_gate) gb = *(const f16x8*)(Ggrp + kt * 32);

        f16x8 bf[4];
#pragma unroll
        for (int j = 0; j < 4; ++j) {
            int nt = (wn >> 4) + j;
            bf[j] = *(const f16x8*)(Wbase + ((size_t)nt * 32 + kt) * 512 + lane * 8);
        }
#pragma unroll
        for (int i = 0; i < 4; ++i) {
            f16x8 a = *(const f16x8*)(&Ash[cur][(wm + i * 16 + lrow) * 32 + quad * 8]);
#pragma unroll
            for (int j = 0; j < 4; ++j)
                acc[i][j] = __builtin_amdgcn_mfma_f32_16x16x32_f16(a, bf[j], acc[i][j], 0, 0, 0);
            if (my_gate)
                gacc[i] = __builtin_amdgcn_mfma_f32_16x16x32_f16(a, gb, gacc[i], 0, 0, 0);
        }
        if (kt < 31)
            *(f16x8*)(&Ash[nxt][aoff]) = pack8(lo, hi);
        __syncthreads();
    }

    // epilogue: h = relu(acc + b1), fp16. C/D: col=lane&15, row=quad*4+reg.
#pragma unroll
    for (int j = 0; j < 4; ++j) {
        int c = wn + j * 16 + lrow;
        float bias = b1[c];
#pragma unroll
        for (int i = 0; i < 4; ++i) {
#pragma unroll
            for (int r = 0; r < 4; ++r) {
                int row = row0 + wm + i * 16 + quad * 4 + r;
                float v = fmaxf(acc[i][j][r] + bias, 0.0f);
                hbuf[((size_t)g * BB + row) * 256 + c] = (f16)v;
            }
        }
    }

    // gate softmax: 16-lane groups share one row's logits (c = lrow)
    if (my_gate) {
        int c = lrow;
        bool valid = (c < ng);
        float bias = valid ? bg[c] : 0.0f;
#pragma unroll
        for (int i = 0; i < 4; ++i) {
#pragma unroll
            for (int r = 0; r < 4; ++r) {
                int row = row0 + wm + i * 16 + quad * 4 + r;
                float logit = valid ? (gacc[i][r] + bias) : -1e30f;
                float mx = logit;
#pragma unroll
                for (int m = 1; m < 16; m <<= 1)
                    mx = fmaxf(mx, __shfl_xor(mx, m, 16));
                float ev = valid ? __expf(logit - mx) : 0.0f;
                float sum = ev;
#pragma unroll
                for (int m = 1; m < 16; m <<= 1)
                    sum += __shfl_xor(sum, m, 16);
                if (valid) gout[(size_t)row * ng + c] = ev / sum;
            }
        }
    }
}

// ---------------------------------------------------------------------------
// Layer-2 + gated combine. grid (128, 3), 512 threads, block = 128r x 256c.
// 8 waves: 4 row-groups (32r) x 2 col-halves (128c). Per expert: h slice
// [128x64] staged via global_load_lds (dbuf, swizzled), W2 frags + bias direct
// from L2 (coalesced B-frag pack). oacc += gate * relu(eacc + b2).
// ---------------------------------------------------------------------------
__global__ __launch_bounds__(512, 4) void l2_kernel(
    const f16* __restrict__ hbuf,    // [3][B][256]
    const f16* __restrict__ W2F,     // [3][4][16][2][64][8]
    const float* __restrict__ b2A, const float* __restrict__ b2S, const float* __restrict__ b2B,
    const float* __restrict__ gates,
    float* __restrict__ out)         // [3][B][256] (A,S,B)
{
    const int o = blockIdx.y;
    const int row0 = blockIdx.x * 128;
    const int tid = threadIdx.x;
    const int lane = tid & 63;
    const int wave = tid >> 6;
    const int wm = (wave >> 1) * 32;
    const int wn = (wave & 1) * 128;
    const int lrow = lane & 15;
    const int quad = lane >> 4;

    const int ng = (o == 1) ? 12 : 8;
    const float* gp = gates + ((o == 0) ? (size_t)0
                             : (o == 1) ? (size_t)BB * 8
                                        : (size_t)BB * 8 + (size_t)BB * 12);

    __shared__ __align__(16) f16 Ash[2][128 * 64];   // h slice, 16 KB per buf
    __shared__ float gsh[128 * 12];

    for (int idx = tid; idx < 128 * ng; idx += 512)
        gsh[idx] = gp[(size_t)(row0 + idx / ng) * ng + (idx % ng)];

    // stage expert 0 into buf 0 (swizzled: chunk = slot ^ (m&7))
    {
        int gi = expert_gi(o, 0);
        const f16* hs = hbuf + ((size_t)gi * BB + row0) * 256;   // e=0
#pragma unroll
        for (int r = 0; r < 2; ++r) {
            int s = r * 512 + tid;
            int m = s >> 3, slot = s & 7;
            int chunk = slot ^ (m & 7);
            load_lds16(hs + (size_t)m * 256 + chunk * 8, &Ash[0][s * 8]);
        }
    }

    f32x4 oacc[2][8] = {};

    for (int k = 0; k < ng; ++k) {
        const int cur = k & 1, nxt = cur ^ 1;
        __syncthreads();             // buf[cur] ready; also fences gsh on k=0

        if (k + 1 < ng) {            // prefetch next expert's h slice
            int gi2 = expert_gi(o, k + 1);
            int e2 = (k + 1) & 3;
            const f16* hs = hbuf + ((size_t)gi2 * BB + row0) * 256 + e2 * 64;
#pragma unroll
            for (int r = 0; r < 2; ++r) {
                int s = r * 512 + tid;
                int m = s >> 3, slot = s & 7;
                int chunk = slot ^ (m & 7);
                load_lds16(hs + (size_t)m * 256 + chunk * 8, &Ash[nxt][s * 8]);
            }
        }

        const int e = k & 3;
        const int gi = expert_gi(o, k);
        const float* b2 = (gi == 0) ? b2A : ((gi == 1) ? b2S : b2B);
        const f16* wb = W2F + (size_t)(gi * 4 + e) * 16384;   // 16*2*512

        f16x8 af[2][2];
#pragma unroll
        for (int i = 0; i < 2; ++i) {
#pragma unroll
            for (int kk = 0; kk < 2; ++kk) {
                int m = wm + i * 16 + lrow;
                int slot = (kk * 4 + quad) ^ (m & 7);
                af[i][kk] = *(const f16x8*)(&Ash[cur][m * 64 + slot * 8]);
            }
        }
#pragma unroll
        for (int j = 0; j < 8; ++j) {
            int nt = (wn >> 4) + j;
            f16x8 bf0 = *(const f16x8*)(wb + ((size_t)nt * 2 + 0) * 512 + lane * 8);
            f16x8 bf1 = *(const f16x8*)(wb + ((size_t)nt * 2 + 1) * 512 + lane * 8);
            int d = wn + j * 16 + lrow;
            float bias = b2[e * 256 + d];
#pragma unroll
            for (int i = 0; i < 2; ++i) {
                f32x4 t = {};
                t = __builtin_amdgcn_mfma_f32_16x16x32_f16(af[i][0], bf0, t, 0, 0, 0);
                t = __builtin_amdgcn_mfma_f32_16x16x32_f16(af[i][1], bf1, t, 0, 0, 0);
#pragma unroll
                for (int r = 0; r < 4; ++r) {
                    int rl = wm + i * 16 + quad * 4 + r;
                    float v = fmaxf(t[r] + bias, 0.0f);
                    oacc[i][j][r] += gsh[rl * ng + k] * v;
                }
            }
        }
    }

#pragma unroll
    for (int j = 0; j < 8; ++j) {
        int d = wn + j * 16 + lrow;
#pragma unroll
        for (int i = 0; i < 2; ++i) {
#pragma unroll
            for (int r = 0; r < 4; ++r) {
                int rl = wm + i * 16 + quad * 4 + r;
                out[((size_t)o * BB + row0 + rl) * 256 + d] = oacc[i][j][r];
            }
        }
    }
}

// ---------------------------------------------------------------------------
extern "C" void kernel_launch(void* const* d_in, const int* in_sizes, int n_in,
                              void* d_out, int out_size, void* d_ws, size_t ws_size,
                              hipStream_t stream)
{
    (void)in_sizes; (void)n_in; (void)out_size; (void)ws_size;

    const float* xA  = (const float*)d_in[0];
    const float* xS  = (const float*)d_in[1];
    const float* xB  = (const float*)d_in[2];
    const float* W1A = (const float*)d_in[3];
    const float* b1A = (const float*)d_in[4];
    const float* W2A = (const float*)d_in[5];
    const float* b2A = (const float*)d_in[6];
    const float* W1S = (const float*)d_in[7];
    const float* b1S = (const float*)d_in[8];
    const float* W2S = (const float*)d_in[9];
    const float* b2S = (const float*)d_in[10];
    const float* W1B = (const float*)d_in[11];
    const float* b1B = (const float*)d_in[12];
    const float* W2B = (const float*)d_in[13];
    const float* b2B = (const float*)d_in[14];
    const float* WgA = (const float*)d_in[15];
    const float* bgA = (const float*)d_in[16];
    const float* WgB = (const float*)d_in[17];
    const float* bgB = (const float*)d_in[18];
    const float* WgS = (const float*)d_in[19];
    const float* bgS = (const float*)d_in[20];

    char* ws = (char*)d_ws;
    f16*   W1F  = (f16*)(ws);                       // 1,572,864 B
    f16*   W2F  = (f16*)(ws + 0x180000);            //   393,216 B
    f16*   Gp2  = (f16*)(ws + 0x1E0000);            //    98,304 B
    f16*   hbuf = (f16*)(ws + 0x200000);            // 25,165,824 B
    float* gate = (float*)(ws + 0x200000 + 0x1800000); // 1,835,008 B

    pack_kernel<<<4032, 256, 0, stream>>>(W1A, W1S, W1B, W2A, W2S, W2B,
                                          WgA, WgS, WgB, W1F, W2F, Gp2);
    l1_kernel<<<dim3(128, 3), 512, 0, stream>>>(
        xA, xS, xB, b1A, b1S, b1B, bgA, bgS, bgB,
        W1F, Gp2, hbuf, gate);
    l2_kernel<<<dim3(128, 3), 512, 0, stream>>>(
        hbuf, W2F, b2A, b2S, b2B, gate, (float*)d_out);
}